// Round 1
// baseline (12899.298 us; speedup 1.0000x reference)
//
#include <hip/hip_runtime.h>
#include <math.h>

#define WIDTH 512
#define LAYERS 6
#define HEADS 8
#define DH 64
#define T_DYN 16
#define NF 128
#define NFR 12            // N = N_FRAMES-1
#define BLK 146           // NF + T_DYN + 2
#define SEQ 1752          // NFR * BLK
#define BATCH 4
#define VOCAB 1024
#define MROWS (BATCH*SEQ) // 7008
#define OUTROWS (BATCH*NFR*NF) // 6144

// ---------------- block reduction helper ----------------
__device__ __forceinline__ float block_reduce(float v, float* sm, int op /*0=sum,1=max*/) {
    for (int o = 32; o > 0; o >>= 1) {
        float other = __shfl_down(v, o);
        v = op ? fmaxf(v, other) : (v + other);
    }
    int lane = threadIdx.x & 63, wid = threadIdx.x >> 6;
    if (lane == 0) sm[wid] = v;
    __syncthreads();
    float r = sm[0];
    int nw = blockDim.x >> 6;
    for (int i = 1; i < nw; i++) r = op ? fmaxf(r, sm[i]) : (r + sm[i]);
    __syncthreads();   // allow sm reuse by a later call
    return r;
}

// ---------------- embed: h = concat(x, delim, f, delim) + pos ----------------
__global__ __launch_bounds__(256) void embed_kernel(
    const float* __restrict__ x, const float* __restrict__ f,
    const float* __restrict__ delim, float* __restrict__ h) {
    int idx = blockIdx.x * 256 + threadIdx.x;      // B*SEQ*WIDTH = 3,588,096
    if (idx >= BATCH * SEQ * WIDTH) return;
    int w = idx & (WIDTH - 1);
    int bs = idx >> 9;
    int s = bs % SEQ;
    int b = bs / SEQ;
    int bi = s / BLK, r = s % BLK;
    float v;
    if (r < NF) {
        v = x[(((size_t)b * NFR + bi) * NF + r) * WIDTH + w];
    } else if (r == NF || r == BLK - 1) {
        v = delim[w];
    } else {
        v = f[(((size_t)b * NFR + bi) * T_DYN + (r - NF - 1)) * WIDTH + w];
    }
    int j = w >> 1;
    float denom = powf(10000.f, (float)j * (1.f / 256.f));
    float ang = (float)s / denom;
    v += (w & 1) ? cosf(ang) : sinf(ang);
    h[idx] = v;
}

// ---------------- LayerNorm (two-pass) ----------------
__global__ __launch_bounds__(256) void ln_kernel(
    const float* __restrict__ x, const float* __restrict__ g,
    const float* __restrict__ b, float* __restrict__ out) {
    __shared__ float sm[8];
    size_t row = blockIdx.x;
    const float* xr = x + row * WIDTH;
    int t = threadIdx.x;
    float v0 = xr[t], v1 = xr[t + 256];
    float mean = block_reduce(v0 + v1, sm, 0) * (1.f / WIDTH);
    float d0 = v0 - mean, d1 = v1 - mean;
    float var = block_reduce(d0 * d0 + d1 * d1, sm, 0) * (1.f / WIDTH);
    float rstd = rsqrtf(var + 1e-5f);
    out[row * WIDTH + t]       = d0 * rstd * g[t] + b[t];
    out[row * WIDTH + t + 256] = d1 * rstd * g[t + 256] + b[t + 256];
}

// ---------------- GEMM: C[M,N] = A[M,K] @ W[N,K]^T + bias ----------------
// MODE 0: store   MODE 1: gelu(v) store   MODE 2: C += v (residual)
#define BM 64
#define BN 64
#define BK 16
template<int MODE>
__global__ __launch_bounds__(256) void gemm_kernel(
    const float* __restrict__ A, const float* __restrict__ W,
    const float* __restrict__ bias, float* __restrict__ C,
    int M, int N, int K) {
    __shared__ float As[BK][BM + 1];
    __shared__ float Ws[BK][BN + 1];
    int tid = threadIdx.x;
    int bm = blockIdx.y * BM;
    int bn = blockIdx.x * BN;
    int ty = tid / 16, tx = tid % 16;
    float acc[4][4] = {};
    int lr = tid / 16;   // row group 0..15
    int lc = tid % 16;   // k within tile
    for (int k0 = 0; k0 < K; k0 += BK) {
        #pragma unroll
        for (int i = 0; i < 4; i++) {
            int row = lr + 16 * i;
            int gm = bm + row;
            As[lc][row] = (gm < M) ? A[(size_t)gm * K + k0 + lc] : 0.f;
            int gn = bn + row;
            Ws[lc][row] = (gn < N) ? W[(size_t)gn * K + k0 + lc] : 0.f;
        }
        __syncthreads();
        #pragma unroll
        for (int kk = 0; kk < BK; kk++) {
            float a[4], w[4];
            #pragma unroll
            for (int i = 0; i < 4; i++) a[i] = As[kk][ty * 4 + i];
            #pragma unroll
            for (int j = 0; j < 4; j++) w[j] = Ws[kk][tx * 4 + j];
            #pragma unroll
            for (int i = 0; i < 4; i++)
                #pragma unroll
                for (int j = 0; j < 4; j++) acc[i][j] += a[i] * w[j];
        }
        __syncthreads();
    }
    #pragma unroll
    for (int i = 0; i < 4; i++) {
        int gm = bm + ty * 4 + i;
        if (gm >= M) continue;
        #pragma unroll
        for (int j = 0; j < 4; j++) {
            int gn = bn + tx * 4 + j;
            if (gn >= N) continue;
            float v = acc[i][j] + (bias ? bias[gn] : 0.f);
            if (MODE == 1) v = 0.5f * v * (1.f + erff(v * 0.70710678118654752f));
            if (MODE == 2) C[(size_t)gm * N + gn] += v;
            else           C[(size_t)gm * N + gn] = v;
        }
    }
}

// ---------------- structured-mask attention ----------------
// allowed keys for a frame-token row in block bi:
//   [bi*146-1] (if bi>0), own frame [bi*146 .. +127],
//   delim+dyn chunks [j*146+128 .. +144] for j = 0..bi
// non-frame rows: self only -> o = v
__device__ __forceinline__ int key_of(int t, int bi) {
    if (bi > 0) { if (t == 0) return bi * BLK - 1; t -= 1; }
    if (t < NF) return bi * BLK + t;
    t -= NF;
    int j = t / 17, r = t % 17;
    return j * BLK + NF + r;
}

__global__ __launch_bounds__(256) void attn_kernel(
    const float* __restrict__ qkv, float* __restrict__ o) {
    int q_pos = blockIdx.x;          // 0..SEQ-1
    int bh = blockIdx.y;             // 0..B*HEADS-1
    int b = bh / HEADS, h = bh % HEADS;
    int tid = threadIdx.x;
    int bi = q_pos / BLK, r = q_pos % BLK;
    const float* qkv_b = qkv + (size_t)b * SEQ * (3 * WIDTH);
    float* orow = o + ((size_t)(b * SEQ + q_pos)) * WIDTH + h * DH;
    if (r >= NF) {               // self-attention only: softmax over {self} = 1
        if (tid < DH) orow[tid] = qkv_b[(size_t)q_pos * (3 * WIDTH) + 2 * WIDTH + h * DH + tid];
        return;
    }
    __shared__ float qs[DH];
    __shared__ float sc[352];
    __shared__ float osum[4][DH];
    __shared__ float sm[8];
    int na = (bi > 0 ? 1 : 0) + NF + 17 * (bi + 1);   // <= 333
    if (tid < DH) qs[tid] = qkv_b[(size_t)q_pos * (3 * WIDTH) + h * DH + tid];
    __syncthreads();
    float lmax = -INFINITY;
    for (int t = tid; t < na; t += 256) {
        int k = key_of(t, bi);
        const float* kv = qkv_b + (size_t)k * (3 * WIDTH) + WIDTH + h * DH;
        float s = 0.f;
        #pragma unroll
        for (int d = 0; d < DH; d++) s += qs[d] * kv[d];
        s *= 0.125f;               // dh^-0.5
        sc[t] = s;
        lmax = fmaxf(lmax, s);
    }
    float gmax = block_reduce(lmax, sm, 1);
    float lsum = 0.f;
    for (int t = tid; t < na; t += 256) {
        float p = expf(sc[t] - gmax);
        sc[t] = p;
        lsum += p;
    }
    float gsum = block_reduce(lsum, sm, 0);
    float inv = 1.f / gsum;
    int d = tid & (DH - 1), c = tid >> 6;
    float acc = 0.f;
    for (int t = c; t < na; t += 4) {
        int k = key_of(t, bi);
        acc += sc[t] * qkv_b[(size_t)k * (3 * WIDTH) + 2 * WIDTH + h * DH + d];
    }
    osum[c][d] = acc;
    __syncthreads();
    if (tid < DH)
        orow[tid] = (osum[0][tid] + osum[1][tid] + osum[2][tid] + osum[3][tid]) * inv;
}

// ---------------- gather frame-token rows for the head ----------------
__global__ __launch_bounds__(256) void gather_kernel(
    const float* __restrict__ h, float* __restrict__ out) {
    int idx = blockIdx.x * 256 + threadIdx.x;     // OUTROWS*WIDTH = 3,145,728
    if (idx >= OUTROWS * WIDTH) return;
    int w = idx & (WIDTH - 1);
    int t = idx >> 9;
    int i = t % NF; t /= NF;
    int n = t % NFR;
    int b = t / NFR;
    int s = n * BLK + i;
    out[idx] = h[((size_t)(b * SEQ + s)) * WIDTH + w];
}

extern "C" void kernel_launch(void* const* d_in, const int* in_sizes, int n_in,
                              void* d_out, int out_size, void* d_ws, size_t ws_size,
                              hipStream_t stream) {
    const float* x     = (const float*)d_in[0];
    const float* f     = (const float*)d_in[1];
    const float* delim = (const float*)d_in[2];
    const float* ln1_s = (const float*)d_in[3];
    const float* ln1_b = (const float*)d_in[4];
    const float* w_qkv = (const float*)d_in[5];
    const float* b_qkv = (const float*)d_in[6];
    const float* w_out = (const float*)d_in[7];
    const float* b_out = (const float*)d_in[8];
    const float* ln2_s = (const float*)d_in[9];
    const float* ln2_b = (const float*)d_in[10];
    const float* w_fc  = (const float*)d_in[11];
    const float* b_fc  = (const float*)d_in[12];
    const float* w_pr  = (const float*)d_in[13];
    const float* b_pr  = (const float*)d_in[14];
    const float* w_hd  = (const float*)d_in[15];
    float* out = (float*)d_out;

    float* ws  = (float*)d_ws;
    float* h   = ws;                                   // MROWS*512  = 3,588,096 f
    float* a   = h + (size_t)MROWS * WIDTH;            // MROWS*512
    float* big = a + (size_t)MROWS * WIDTH;            // MROWS*2048 = 14,352,384 f

    embed_kernel<<<(BATCH * SEQ * WIDTH) / 256, 256, 0, stream>>>(x, f, delim, h);

    for (int l = 0; l < LAYERS; l++) {
        ln_kernel<<<MROWS, 256, 0, stream>>>(h, ln1_s + l * WIDTH, ln1_b + l * WIDTH, a);
        gemm_kernel<0><<<dim3(1536 / BN, (MROWS + BM - 1) / BM), 256, 0, stream>>>(
            a, w_qkv + (size_t)l * 1536 * WIDTH, b_qkv + (size_t)l * 1536, big,
            MROWS, 1536, WIDTH);
        attn_kernel<<<dim3(SEQ, BATCH * HEADS), 256, 0, stream>>>(big, a);
        gemm_kernel<2><<<dim3(WIDTH / BN, (MROWS + BM - 1) / BM), 256, 0, stream>>>(
            a, w_out + (size_t)l * WIDTH * WIDTH, b_out + (size_t)l * WIDTH, h,
            MROWS, WIDTH, WIDTH);
        ln_kernel<<<MROWS, 256, 0, stream>>>(h, ln2_s + l * WIDTH, ln2_b + l * WIDTH, a);
        gemm_kernel<1><<<dim3(2048 / BN, (MROWS + BM - 1) / BM), 256, 0, stream>>>(
            a, w_fc + (size_t)l * 2048 * WIDTH, b_fc + (size_t)l * 2048, big,
            MROWS, 2048, WIDTH);
        gemm_kernel<2><<<dim3(WIDTH / BN, (MROWS + BM - 1) / BM), 256, 0, stream>>>(
            big, w_pr + (size_t)l * WIDTH * 2048, b_pr + (size_t)l * WIDTH, h,
            MROWS, WIDTH, 2048);
    }

    gather_kernel<<<(OUTROWS * WIDTH) / 256, 256, 0, stream>>>(h, a);
    gemm_kernel<0><<<dim3(VOCAB / BN, OUTROWS / BM), 256, 0, stream>>>(
        a, w_hd, nullptr, out, OUTROWS, VOCAB, WIDTH);
}

// Round 2
// 3413.099 us; speedup vs baseline: 3.7794x; 3.7794x over previous
//
#include <hip/hip_runtime.h>
#include <math.h>

#define WIDTH 512
#define LAYERS 6
#define HEADS 8
#define DH 64
#define T_DYN 16
#define NF 128
#define NFR 12            // N = N_FRAMES-1
#define BLK 146           // NF + T_DYN + 2
#define SEQ 1752          // NFR * BLK
#define BATCH 4
#define VOCAB 1024
#define MROWS (BATCH*SEQ)      // 7008
#define OUTROWS (BATCH*NFR*NF) // 6144

typedef __bf16 bf16_t;
typedef __bf16 bf16x8 __attribute__((ext_vector_type(8)));
typedef __bf16 bf16x4 __attribute__((ext_vector_type(4)));
typedef float f32x4 __attribute__((ext_vector_type(4)));

// ---------------- block reduction helper (LN) ----------------
__device__ __forceinline__ float block_reduce_sum(float v, float* sm) {
    for (int o = 32; o > 0; o >>= 1) v += __shfl_down(v, o);
    int lane = threadIdx.x & 63, wid = threadIdx.x >> 6;
    if (lane == 0) sm[wid] = v;
    __syncthreads();
    float r = sm[0];
    int nw = blockDim.x >> 6;
    for (int i = 1; i < nw; i++) r += sm[i];
    __syncthreads();
    return r;
}

// ---------------- fp32 -> bf16 cast (weights) ----------------
__global__ __launch_bounds__(256) void cast_kernel(
    const float* __restrict__ in, bf16_t* __restrict__ out, int n4) {
    int i = blockIdx.x * 256 + threadIdx.x;
    if (i >= n4) return;
    float4 v = ((const float4*)in)[i];
    bf16x4 o = { (bf16_t)v.x, (bf16_t)v.y, (bf16_t)v.z, (bf16_t)v.w };
    *(bf16x4*)(out + (size_t)i * 4) = o;
}

// ---------------- embed: h = concat(x, delim, f, delim) + pos (fp32) ----------------
__global__ __launch_bounds__(256) void embed_kernel(
    const float* __restrict__ x, const float* __restrict__ f,
    const float* __restrict__ delim, float* __restrict__ h) {
    int idx = blockIdx.x * 256 + threadIdx.x;
    if (idx >= BATCH * SEQ * WIDTH) return;
    int w = idx & (WIDTH - 1);
    int bs = idx >> 9;
    int s = bs % SEQ;
    int b = bs / SEQ;
    int bi = s / BLK, r = s % BLK;
    float v;
    if (r < NF) {
        v = x[(((size_t)b * NFR + bi) * NF + r) * WIDTH + w];
    } else if (r == NF || r == BLK - 1) {
        v = delim[w];
    } else {
        v = f[(((size_t)b * NFR + bi) * T_DYN + (r - NF - 1)) * WIDTH + w];
    }
    int j = w >> 1;
    float denom = powf(10000.f, (float)j * (1.f / 256.f));
    float ang = (float)s / denom;
    v += (w & 1) ? cosf(ang) : sinf(ang);
    h[idx] = v;
}

// ---------------- LayerNorm: fp32 in -> bf16 out ----------------
__global__ __launch_bounds__(256) void ln_kernel(
    const float* __restrict__ x, const float* __restrict__ g,
    const float* __restrict__ b, bf16_t* __restrict__ out) {
    __shared__ float sm[4];
    size_t row = blockIdx.x;
    const float* xr = x + row * WIDTH;
    int t = threadIdx.x;
    float v0 = xr[t], v1 = xr[t + 256];
    float mean = block_reduce_sum(v0 + v1, sm) * (1.f / WIDTH);
    float d0 = v0 - mean, d1 = v1 - mean;
    float var = block_reduce_sum(d0 * d0 + d1 * d1, sm) * (1.f / WIDTH);
    float rstd = rsqrtf(var + 1e-5f);
    out[row * WIDTH + t]       = (bf16_t)(d0 * rstd * g[t] + b[t]);
    out[row * WIDTH + t + 256] = (bf16_t)(d1 * rstd * g[t + 256] + b[t + 256]);
}

// ---------------- bf16 MFMA GEMM: C[M,N] = A[M,K] @ W[N,K]^T + bias ----------------
// MODE 0: store fp32   MODE 1: gelu -> bf16   MODE 2: fp32 C += v   MODE 3: store bf16
#define TM 128
#define TN 128
#define TK 32
template<int MODE>
__global__ __launch_bounds__(256) void gemm_bf16(
    const bf16_t* __restrict__ A, const bf16_t* __restrict__ W,
    const float* __restrict__ bias, float* __restrict__ Cf, bf16_t* __restrict__ Cb,
    int M, int N, int K) {
    __shared__ bf16_t As[TM * TK];
    __shared__ bf16_t Ws[TN * TK];
    int tid = threadIdx.x;
    int bm = blockIdx.y * TM, bn = blockIdx.x * TN;
    int lane = tid & 63, wid = tid >> 6;
    int wy = wid >> 1, wx = wid & 1;
    int lr = lane & 15, lq = lane >> 4;
    f32x4 acc[4][4];
    #pragma unroll
    for (int i = 0; i < 4; i++)
        #pragma unroll
        for (int j = 0; j < 4; j++)
            acc[i][j] = (f32x4){0.f, 0.f, 0.f, 0.f};
    int srow = tid >> 2;   // 0..63
    int sc_  = tid & 3;    // chunk 0..3 (8 bf16 each)
    const bf16_t z0 = (bf16_t)0.f;
    for (int k0 = 0; k0 < K; k0 += TK) {
        #pragma unroll
        for (int it = 0; it < 2; it++) {
            int row = srow + it * 64;
            int swz = (sc_ + (row >> 1)) & 3;
            int gm = bm + row;
            bf16x8 av = {z0, z0, z0, z0, z0, z0, z0, z0};
            if (gm < M) av = *(const bf16x8*)(A + (size_t)gm * K + k0 + sc_ * 8);
            *(bf16x8*)(As + row * TK + swz * 8) = av;
            bf16x8 wv = *(const bf16x8*)(W + (size_t)(bn + row) * K + k0 + sc_ * 8);
            *(bf16x8*)(Ws + row * TK + swz * 8) = wv;
        }
        __syncthreads();
        bf16x8 af[4], bfr[4];
        #pragma unroll
        for (int i = 0; i < 4; i++) {
            int rowa = wy * 64 + i * 16 + lr;
            int swza = (lq + (rowa >> 1)) & 3;
            af[i] = *(const bf16x8*)(As + rowa * TK + swza * 8);
            int rowb = wx * 64 + i * 16 + lr;
            int swzb = (lq + (rowb >> 1)) & 3;
            bfr[i] = *(const bf16x8*)(Ws + rowb * TK + swzb * 8);
        }
        #pragma unroll
        for (int i = 0; i < 4; i++)
            #pragma unroll
            for (int j = 0; j < 4; j++)
                acc[i][j] = __builtin_amdgcn_mfma_f32_16x16x32_bf16(af[i], bfr[j], acc[i][j], 0, 0, 0);
        __syncthreads();
    }
    #pragma unroll
    for (int j = 0; j < 4; j++) {
        int col = bn + wx * 64 + j * 16 + lr;
        float bj = bias ? bias[col] : 0.f;
        #pragma unroll
        for (int i = 0; i < 4; i++) {
            int rbase = bm + wy * 64 + i * 16 + lq * 4;
            #pragma unroll
            for (int r = 0; r < 4; r++) {
                int gm = rbase + r;
                if (gm >= M) continue;
                float v = acc[i][j][r] + bj;
                if (MODE == 1) {
                    v = 0.5f * v * (1.f + erff(v * 0.70710678118654752f));
                    Cb[(size_t)gm * N + col] = (bf16_t)v;
                } else if (MODE == 2) {
                    Cf[(size_t)gm * N + col] += v;
                } else if (MODE == 3) {
                    Cb[(size_t)gm * N + col] = (bf16_t)v;
                } else {
                    Cf[(size_t)gm * N + col] = v;
                }
            }
        }
    }
}

// ---------------- structured-mask attention ----------------
__device__ __forceinline__ int key_of(int t, int bi) {
    if (bi > 0) { if (t == 0) return bi * BLK - 1; t -= 1; }
    if (t < NF) return bi * BLK + t;
    t -= NF;
    int j = t / 17, r = t % 17;
    return j * BLK + NF + r;
}

// one block per (frame-block, head, batch); 128 threads = 128 q rows; online softmax
__global__ __launch_bounds__(128) void attn_frame(
    const bf16_t* __restrict__ qkv, bf16_t* __restrict__ o) {
    int bi = blockIdx.x;
    int h = blockIdx.y, b = blockIdx.z;
    int tid = threadIdx.x;
    int sq = bi * BLK + tid;
    const bf16_t* base = qkv + (size_t)b * SEQ * (3 * WIDTH);
    __shared__ float Ks[16][64];
    __shared__ float Vs[16][64];
    __shared__ int slist[352];
    int na = (bi > 0 ? 1 : 0) + NF + 17 * (bi + 1);
    for (int t = tid; t < na; t += 128) slist[t] = key_of(t, bi);

    float q[64], ov[64];
    {
        const bf16_t* qp = base + (size_t)sq * (3 * WIDTH) + h * DH;
        #pragma unroll
        for (int i = 0; i < 8; i++) {
            bf16x8 v = *(const bf16x8*)(qp + i * 8);
            #pragma unroll
            for (int j = 0; j < 8; j++) q[i * 8 + j] = (float)v[j];
        }
    }
    #pragma unroll
    for (int d = 0; d < 64; d++) ov[d] = 0.f;
    float m = -INFINITY, l = 0.f;
    __syncthreads();   // slist ready

    int nch = (na + 15) / 16;
    int srow = tid >> 3, seg = tid & 7;
    for (int ci = 0; ci < nch; ci++) {
        // stage 16 keys' K and V (bf16 -> fp32) into LDS
        {
            int tkey = ci * 16 + srow;
            float kf[8], vf[8];
            if (tkey < na) {
                int skey = slist[tkey];
                const bf16_t* kp = base + (size_t)skey * (3 * WIDTH) + WIDTH + h * DH + seg * 8;
                bf16x8 kv = *(const bf16x8*)kp;
                bf16x8 vv = *(const bf16x8*)(kp + WIDTH);
                #pragma unroll
                for (int j = 0; j < 8; j++) { kf[j] = (float)kv[j]; vf[j] = (float)vv[j]; }
            } else {
                #pragma unroll
                for (int j = 0; j < 8; j++) { kf[j] = 0.f; vf[j] = 0.f; }
            }
            #pragma unroll
            for (int j = 0; j < 8; j++) { Ks[srow][seg * 8 + j] = kf[j]; Vs[srow][seg * 8 + j] = vf[j]; }
        }
        __syncthreads();
        // scores: sc[kk] = q . K[kk]
        float sc[16];
        #pragma unroll
        for (int kk = 0; kk < 16; kk++) sc[kk] = 0.f;
        #pragma unroll
        for (int d4 = 0; d4 < 16; d4++) {
            float a0 = q[d4 * 4], a1 = q[d4 * 4 + 1], a2 = q[d4 * 4 + 2], a3 = q[d4 * 4 + 3];
            #pragma unroll
            for (int kk = 0; kk < 16; kk++) {
                float4 k4 = *(const float4*)&Ks[kk][d4 * 4];
                sc[kk] = fmaf(a0, k4.x, fmaf(a1, k4.y, fmaf(a2, k4.z, fmaf(a3, k4.w, sc[kk]))));
            }
        }
        int base_k = ci * 16;
        float mnew = m;
        #pragma unroll
        for (int kk = 0; kk < 16; kk++) {
            sc[kk] = (base_k + kk < na) ? sc[kk] * 0.125f : -INFINITY;
            mnew = fmaxf(mnew, sc[kk]);
        }
        float alpha = __expf(m - mnew);
        float p[16], psum = 0.f;
        #pragma unroll
        for (int kk = 0; kk < 16; kk++) { p[kk] = __expf(sc[kk] - mnew); psum += p[kk]; }
        l = l * alpha + psum;
        m = mnew;
        #pragma unroll
        for (int d = 0; d < 64; d++) ov[d] *= alpha;
        #pragma unroll
        for (int kk = 0; kk < 16; kk++) {
            float pk = p[kk];
            #pragma unroll
            for (int d4 = 0; d4 < 16; d4++) {
                float4 v4 = *(const float4*)&Vs[kk][d4 * 4];
                ov[d4 * 4]     = fmaf(pk, v4.x, ov[d4 * 4]);
                ov[d4 * 4 + 1] = fmaf(pk, v4.y, ov[d4 * 4 + 1]);
                ov[d4 * 4 + 2] = fmaf(pk, v4.z, ov[d4 * 4 + 2]);
                ov[d4 * 4 + 3] = fmaf(pk, v4.w, ov[d4 * 4 + 3]);
            }
        }
        __syncthreads();
    }
    float inv = 1.f / l;
    bf16_t* op = o + ((size_t)(b * SEQ) + sq) * WIDTH + h * DH;
    #pragma unroll
    for (int i = 0; i < 8; i++) {
        bf16x8 w;
        #pragma unroll
        for (int j = 0; j < 8; j++) w[j] = (bf16_t)(ov[i * 8 + j] * inv);
        *(bf16x8*)(op + i * 8) = w;
    }
}

// delim/dynamics rows attend only to themselves: o = v
__global__ __launch_bounds__(256) void attn_copy(
    const bf16_t* __restrict__ qkv, bf16_t* __restrict__ o) {
    int idx = blockIdx.x * 256 + threadIdx.x;   // 864 rows * 64 segs
    if (idx >= BATCH * NFR * 18 * 64) return;
    int seg = idx & 63;
    int row = idx >> 6;
    int b = row / (NFR * 18);
    int rem = row % (NFR * 18);
    int bi = rem / 18;
    int r = rem % 18 + NF;
    int s = bi * BLK + r;
    const bf16_t* src = qkv + ((size_t)(b * SEQ + s) * (3 * WIDTH) + 2 * WIDTH + seg * 8);
    bf16_t* dst = o + ((size_t)(b * SEQ + s) * WIDTH + seg * 8);
    *(bf16x8*)dst = *(const bf16x8*)src;
}

// ---------------- gather frame-token rows (fp32 h -> bf16) ----------------
__global__ __launch_bounds__(256) void gather_kernel(
    const float* __restrict__ h, bf16_t* __restrict__ out) {
    int idx = blockIdx.x * 256 + threadIdx.x;   // OUTROWS*WIDTH/4
    if (idx >= OUTROWS * WIDTH / 4) return;
    int w = (idx * 4) & (WIDTH - 1);
    int t = (idx * 4) >> 9;
    int i = t % NF; t /= NF;
    int n = t % NFR;
    int b = t / NFR;
    int s = n * BLK + i;
    float4 v = *(const float4*)(h + ((size_t)(b * SEQ + s)) * WIDTH + w);
    bf16x4 o = { (bf16_t)v.x, (bf16_t)v.y, (bf16_t)v.z, (bf16_t)v.w };
    *(bf16x4*)(out + (size_t)idx * 4) = o;
}

extern "C" void kernel_launch(void* const* d_in, const int* in_sizes, int n_in,
                              void* d_out, int out_size, void* d_ws, size_t ws_size,
                              hipStream_t stream) {
    const float* x     = (const float*)d_in[0];
    const float* f     = (const float*)d_in[1];
    const float* delim = (const float*)d_in[2];
    const float* ln1_s = (const float*)d_in[3];
    const float* ln1_b = (const float*)d_in[4];
    const float* w_qkv = (const float*)d_in[5];
    const float* b_qkv = (const float*)d_in[6];
    const float* w_out = (const float*)d_in[7];
    const float* b_out = (const float*)d_in[8];
    const float* ln2_s = (const float*)d_in[9];
    const float* ln2_b = (const float*)d_in[10];
    const float* w_fc  = (const float*)d_in[11];
    const float* b_fc  = (const float*)d_in[12];
    const float* w_pr  = (const float*)d_in[13];
    const float* b_pr  = (const float*)d_in[14];
    const float* w_hd  = (const float*)d_in[15];
    float* out = (float*)d_out;

    // workspace layout (bytes): total ~68.1 MB (known-good ws >= 86.1 MB)
    char* base = (char*)d_ws;
    float*  h      = (float*)base;                 base += (size_t)MROWS * WIDTH * 4;     // 14.35 MB
    bf16_t* a_bf   = (bf16_t*)base;                base += (size_t)MROWS * WIDTH * 2;     // 7.18 MB
    bf16_t* big_bf = (bf16_t*)base;                base += (size_t)MROWS * 2048 * 2;      // 28.7 MB (qkv 1536 / gelu 2048 shared)
    bf16_t* wi_bf  = (bf16_t*)base;                base += (size_t)LAYERS * 1536 * 512 * 2;
    bf16_t* wo_bf  = (bf16_t*)base;                base += (size_t)LAYERS * 512 * 512 * 2;
    bf16_t* wh_bf  = (bf16_t*)base;                base += (size_t)VOCAB * 512 * 2;
    bf16_t* wfc_bf = (bf16_t*)base;                base += (size_t)2048 * 512 * 2;
    bf16_t* wpr_bf = (bf16_t*)base;                base += (size_t)512 * 2048 * 2;

    cast_kernel<<<LAYERS * 1536 * 512 / 1024, 256, 0, stream>>>(w_qkv, wi_bf, LAYERS * 1536 * 512 / 4);
    cast_kernel<<<LAYERS * 512 * 512 / 1024, 256, 0, stream>>>(w_out, wo_bf, LAYERS * 512 * 512 / 4);
    cast_kernel<<<VOCAB * 512 / 1024, 256, 0, stream>>>(w_hd, wh_bf, VOCAB * 512 / 4);

    embed_kernel<<<(BATCH * SEQ * WIDTH) / 256, 256, 0, stream>>>(x, f, delim, h);

    const int MT = (MROWS + TM - 1) / TM;   // 55
    for (int l = 0; l < LAYERS; l++) {
        ln_kernel<<<MROWS, 256, 0, stream>>>(h, ln1_s + l * WIDTH, ln1_b + l * WIDTH, a_bf);
        gemm_bf16<3><<<dim3(1536 / TN, MT), 256, 0, stream>>>(
            a_bf, wi_bf + (size_t)l * 1536 * 512, b_qkv + (size_t)l * 1536,
            nullptr, big_bf, MROWS, 1536, 512);
        attn_frame<<<dim3(NFR, HEADS, BATCH), 128, 0, stream>>>(big_bf, a_bf);
        attn_copy<<<(BATCH * NFR * 18 * 64 + 255) / 256, 256, 0, stream>>>(big_bf, a_bf);
        gemm_bf16<2><<<dim3(512 / TN, MT), 256, 0, stream>>>(
            a_bf, wo_bf + (size_t)l * 512 * 512, b_out + (size_t)l * 512,
            h, nullptr, MROWS, 512, 512);
        ln_kernel<<<MROWS, 256, 0, stream>>>(h, ln2_s + l * WIDTH, ln2_b + l * WIDTH, a_bf);
        cast_kernel<<<2048 * 512 / 1024, 256, 0, stream>>>(w_fc + (size_t)l * 2048 * 512, wfc_bf, 2048 * 512 / 4);
        gemm_bf16<1><<<dim3(2048 / TN, MT), 256, 0, stream>>>(
            a_bf, wfc_bf, b_fc + (size_t)l * 2048,
            nullptr, big_bf, MROWS, 2048, 512);
        cast_kernel<<<512 * 2048 / 1024, 256, 0, stream>>>(w_pr + (size_t)l * 512 * 2048, wpr_bf, 512 * 2048 / 4);
        gemm_bf16<2><<<dim3(512 / TN, MT), 256, 0, stream>>>(
            big_bf, wpr_bf, b_pr + (size_t)l * 512,
            h, nullptr, MROWS, 512, 2048);
    }

    gather_kernel<<<(OUTROWS * WIDTH / 4) / 256, 256, 0, stream>>>(h, a_bf);
    gemm_bf16<0><<<dim3(VOCAB / TN, OUTROWS / TM), 256, 0, stream>>>(
        a_bf, wh_bf, nullptr, out, nullptr, OUTROWS, VOCAB, 512);
}

// Round 3
// 1638.969 us; speedup vs baseline: 7.8704x; 2.0825x over previous
//
#include <hip/hip_runtime.h>
#include <math.h>

#define WIDTH 512
#define LAYERS 6
#define HEADS 8
#define DH 64
#define T_DYN 16
#define NF 128
#define NFR 12            // N = N_FRAMES-1
#define BLK 146           // NF + T_DYN + 2
#define SEQ 1752          // NFR * BLK
#define BATCH 4
#define VOCAB 1024
#define MROWS (BATCH*SEQ)      // 7008
#define OUTROWS (BATCH*NFR*NF) // 6144

typedef __bf16 bf16_t;
typedef __bf16 bf16x8 __attribute__((ext_vector_type(8)));
typedef __bf16 bf16x4 __attribute__((ext_vector_type(4)));
typedef float f32x4 __attribute__((ext_vector_type(4)));

// ---------------- block reduction helper (LN) ----------------
__device__ __forceinline__ float block_reduce_sum(float v, float* sm) {
    for (int o = 32; o > 0; o >>= 1) v += __shfl_down(v, o);
    int lane = threadIdx.x & 63, wid = threadIdx.x >> 6;
    if (lane == 0) sm[wid] = v;
    __syncthreads();
    float r = sm[0];
    int nw = blockDim.x >> 6;
    for (int i = 1; i < nw; i++) r += sm[i];
    __syncthreads();
    return r;
}

// ---------------- fp32 -> bf16 cast (weights) ----------------
__global__ __launch_bounds__(256) void cast_kernel(
    const float* __restrict__ in, bf16_t* __restrict__ out, int n4) {
    int i = blockIdx.x * 256 + threadIdx.x;
    if (i >= n4) return;
    float4 v = ((const float4*)in)[i];
    bf16x4 o = { (bf16_t)v.x, (bf16_t)v.y, (bf16_t)v.z, (bf16_t)v.w };
    *(bf16x4*)(out + (size_t)i * 4) = o;
}

// ---------------- embed: h = concat(x, delim, f, delim) + pos (fp32) ----------------
__global__ __launch_bounds__(256) void embed_kernel(
    const float* __restrict__ x, const float* __restrict__ f,
    const float* __restrict__ delim, float* __restrict__ h) {
    int idx = blockIdx.x * 256 + threadIdx.x;
    if (idx >= BATCH * SEQ * WIDTH) return;
    int w = idx & (WIDTH - 1);
    int bs = idx >> 9;
    int s = bs % SEQ;
    int b = bs / SEQ;
    int bi = s / BLK, r = s % BLK;
    float v;
    if (r < NF) {
        v = x[(((size_t)b * NFR + bi) * NF + r) * WIDTH + w];
    } else if (r == NF || r == BLK - 1) {
        v = delim[w];
    } else {
        v = f[(((size_t)b * NFR + bi) * T_DYN + (r - NF - 1)) * WIDTH + w];
    }
    int j = w >> 1;
    float denom = powf(10000.f, (float)j * (1.f / 256.f));
    float ang = (float)s / denom;
    v += (w & 1) ? cosf(ang) : sinf(ang);
    h[idx] = v;
}

// ---------------- LayerNorm: fp32 in -> bf16 out ----------------
__global__ __launch_bounds__(256) void ln_kernel(
    const float* __restrict__ x, const float* __restrict__ g,
    const float* __restrict__ b, bf16_t* __restrict__ out) {
    __shared__ float sm[4];
    size_t row = blockIdx.x;
    const float* xr = x + row * WIDTH;
    int t = threadIdx.x;
    float v0 = xr[t], v1 = xr[t + 256];
    float mean = block_reduce_sum(v0 + v1, sm) * (1.f / WIDTH);
    float d0 = v0 - mean, d1 = v1 - mean;
    float var = block_reduce_sum(d0 * d0 + d1 * d1, sm) * (1.f / WIDTH);
    float rstd = rsqrtf(var + 1e-5f);
    out[row * WIDTH + t]       = (bf16_t)(d0 * rstd * g[t] + b[t]);
    out[row * WIDTH + t + 256] = (bf16_t)(d1 * rstd * g[t + 256] + b[t + 256]);
}

// ---------------- bf16 MFMA GEMM: C[M,N] = A[M,K] @ W[N,K]^T + bias ----------------
// MODE 0: store fp32   MODE 1: gelu -> bf16   MODE 2: fp32 C += v   MODE 3: store bf16
#define TM 128
#define TN 128
#define TK 32
template<int MODE>
__global__ __launch_bounds__(256) void gemm_bf16(
    const bf16_t* __restrict__ A, const bf16_t* __restrict__ W,
    const float* __restrict__ bias, float* __restrict__ Cf, bf16_t* __restrict__ Cb,
    int M, int N, int K) {
    __shared__ bf16_t As[TM * TK];
    __shared__ bf16_t Ws[TN * TK];
    int tid = threadIdx.x;
    int bm = blockIdx.y * TM, bn = blockIdx.x * TN;
    int lane = tid & 63, wid = tid >> 6;
    int wy = wid >> 1, wx = wid & 1;
    int lr = lane & 15, lq = lane >> 4;
    f32x4 acc[4][4];
    #pragma unroll
    for (int i = 0; i < 4; i++)
        #pragma unroll
        for (int j = 0; j < 4; j++)
            acc[i][j] = (f32x4){0.f, 0.f, 0.f, 0.f};
    int srow = tid >> 2;   // 0..63
    int sc_  = tid & 3;    // chunk 0..3 (8 bf16 each)
    const bf16_t z0 = (bf16_t)0.f;
    for (int k0 = 0; k0 < K; k0 += TK) {
        #pragma unroll
        for (int it = 0; it < 2; it++) {
            int row = srow + it * 64;
            int swz = (sc_ + (row >> 1)) & 3;
            int gm = bm + row;
            bf16x8 av = {z0, z0, z0, z0, z0, z0, z0, z0};
            if (gm < M) av = *(const bf16x8*)(A + (size_t)gm * K + k0 + sc_ * 8);
            *(bf16x8*)(As + row * TK + swz * 8) = av;
            bf16x8 wv = *(const bf16x8*)(W + (size_t)(bn + row) * K + k0 + sc_ * 8);
            *(bf16x8*)(Ws + row * TK + swz * 8) = wv;
        }
        __syncthreads();
        bf16x8 af[4], bfr[4];
        #pragma unroll
        for (int i = 0; i < 4; i++) {
            int rowa = wy * 64 + i * 16 + lr;
            int swza = (lq + (rowa >> 1)) & 3;
            af[i] = *(const bf16x8*)(As + rowa * TK + swza * 8);
            int rowb = wx * 64 + i * 16 + lr;
            int swzb = (lq + (rowb >> 1)) & 3;
            bfr[i] = *(const bf16x8*)(Ws + rowb * TK + swzb * 8);
        }
        #pragma unroll
        for (int i = 0; i < 4; i++)
            #pragma unroll
            for (int j = 0; j < 4; j++)
                acc[i][j] = __builtin_amdgcn_mfma_f32_16x16x32_bf16(af[i], bfr[j], acc[i][j], 0, 0, 0);
        __syncthreads();
    }
    #pragma unroll
    for (int j = 0; j < 4; j++) {
        int col = bn + wx * 64 + j * 16 + lr;
        float bj = bias ? bias[col] : 0.f;
        #pragma unroll
        for (int i = 0; i < 4; i++) {
            int rbase = bm + wy * 64 + i * 16 + lq * 4;
            #pragma unroll
            for (int r = 0; r < 4; r++) {
                int gm = rbase + r;
                if (gm >= M) continue;
                float v = acc[i][j][r] + bj;
                if (MODE == 1) {
                    v = 0.5f * v * (1.f + erff(v * 0.70710678118654752f));
                    Cb[(size_t)gm * N + col] = (bf16_t)v;
                } else if (MODE == 2) {
                    Cf[(size_t)gm * N + col] += v;
                } else if (MODE == 3) {
                    Cb[(size_t)gm * N + col] = (bf16_t)v;
                } else {
                    Cf[(size_t)gm * N + col] = v;
                }
            }
        }
    }
}

// ---------------- structured-mask attention (MFMA) ----------------
__device__ __forceinline__ int key_of(int t, int bi) {
    if (bi > 0) { if (t == 0) return bi * BLK - 1; t -= 1; }
    if (t < NF) return bi * BLK + t;
    t -= NF;
    int j = t / 17, r = t % 17;
    return j * BLK + NF + r;
}

#define KC 64           // keys per chunk
#define KR 72           // padded LDS row length

// block = (bi, h, b), 256 threads = 4 waves; wave w owns q rows [w*32, w*32+32)
__global__ __launch_bounds__(256) void attn_mfma(
    const bf16_t* __restrict__ qkv, bf16_t* __restrict__ o) {
    int bi = blockIdx.x;
    int h = blockIdx.y, b = blockIdx.z;
    int tid = threadIdx.x;
    int lane = tid & 63, wid = tid >> 6;
    int col = lane & 15, lq = lane >> 4;
    int qr0 = wid * 32;
    const bf16_t* base = qkv + (size_t)b * SEQ * (3 * WIDTH);

    __shared__ bf16_t Ks[KC * KR];        // [key][dim], pad 72
    __shared__ bf16_t Vt[DH * KR];        // [dim][key], pad 72
    __shared__ bf16_t Ps[4][32 * KR];     // per-wave P / O staging
    __shared__ int slist[352];

    int na = (bi > 0 ? 1 : 0) + NF + 17 * (bi + 1);   // <= 333
    for (int t = tid; t < na; t += 256) slist[t] = key_of(t, bi);

    // Q A-fragments: af_q[i][m], i = q sub-tile (16 rows), m = k chunk (32 dims)
    bf16x8 af_q[2][2];
    #pragma unroll
    for (int i = 0; i < 2; i++) {
        int s = bi * BLK + qr0 + i * 16 + col;
        const bf16_t* qp = base + (size_t)s * (3 * WIDTH) + h * DH;
        #pragma unroll
        for (int m = 0; m < 2; m++)
            af_q[i][m] = *(const bf16x8*)(qp + m * 32 + lq * 8);
    }

    f32x4 Oacc[2][4];
    #pragma unroll
    for (int i = 0; i < 2; i++)
        #pragma unroll
        for (int od = 0; od < 4; od++)
            Oacc[i][od] = (f32x4){0.f, 0.f, 0.f, 0.f};
    float m_r[2][4], l_r[2][4];
    #pragma unroll
    for (int i = 0; i < 2; i++)
        #pragma unroll
        for (int r = 0; r < 4; r++) { m_r[i][r] = -INFINITY; l_r[i][r] = 0.f; }

    __syncthreads();   // slist ready

    int nch = (na + KC - 1) / KC;
    const bf16_t z0 = (bf16_t)0.f;
    for (int ci = 0; ci < nch; ci++) {
        int kbase = ci * KC;
        // ---- stage K (row-major) and V^T (dim-major) ----
        #pragma unroll
        for (int it = 0; it < 2; it++) {
            int idx = tid + it * 256;      // 0..511
            int key = idx >> 3, g = idx & 7;
            int tkey = kbase + key;
            bf16x8 kv = {z0,z0,z0,z0,z0,z0,z0,z0};
            bf16x8 vv = kv;
            if (tkey < na) {
                int sk = slist[tkey];
                const bf16_t* kp = base + (size_t)sk * (3 * WIDTH) + WIDTH + h * DH + g * 8;
                kv = *(const bf16x8*)kp;
                vv = *(const bf16x8*)(kp + WIDTH);
            }
            *(bf16x8*)(Ks + key * KR + g * 8) = kv;
            #pragma unroll
            for (int j = 0; j < 8; j++) Vt[(g * 8 + j) * KR + key] = vv[j];
        }
        __syncthreads();

        // ---- S = Q K^T for this chunk: Sacc[i][kj] covers rows i*16.., keys kj*16.. ----
        f32x4 Sacc[2][4];
        #pragma unroll
        for (int i = 0; i < 2; i++)
            #pragma unroll
            for (int kj = 0; kj < 4; kj++)
                Sacc[i][kj] = (f32x4){0.f, 0.f, 0.f, 0.f};
        #pragma unroll
        for (int m = 0; m < 2; m++) {
            #pragma unroll
            for (int kj = 0; kj < 4; kj++) {
                bf16x8 bf_k = *(const bf16x8*)(Ks + (kj * 16 + col) * KR + m * 32 + lq * 8);
                #pragma unroll
                for (int i = 0; i < 2; i++)
                    Sacc[i][kj] = __builtin_amdgcn_mfma_f32_16x16x32_bf16(af_q[i][m], bf_k, Sacc[i][kj], 0, 0, 0);
            }
        }

        // ---- mask + scale + online softmax (rows = (lq)*4+r, cols = kj*16+col) ----
        float alpha_[2][4];
        #pragma unroll
        for (int i = 0; i < 2; i++) {
            #pragma unroll
            for (int r = 0; r < 4; r++) {
                #pragma unroll
                for (int kj = 0; kj < 4; kj++) {
                    int kidx = kbase + kj * 16 + col;
                    float s = Sacc[i][kj][r] * 0.125f;
                    Sacc[i][kj][r] = (kidx < na) ? s : -INFINITY;
                }
                float mx = fmaxf(fmaxf(Sacc[i][0][r], Sacc[i][1][r]),
                                 fmaxf(Sacc[i][2][r], Sacc[i][3][r]));
                mx = fmaxf(mx, __shfl_xor(mx, 1));
                mx = fmaxf(mx, __shfl_xor(mx, 2));
                mx = fmaxf(mx, __shfl_xor(mx, 4));
                mx = fmaxf(mx, __shfl_xor(mx, 8));
                float mn = fmaxf(m_r[i][r], mx);
                float al = __expf(m_r[i][r] - mn);
                float ps = 0.f;
                #pragma unroll
                for (int kj = 0; kj < 4; kj++) {
                    float p = __expf(Sacc[i][kj][r] - mn);
                    Sacc[i][kj][r] = p;
                    ps += p;
                }
                ps += __shfl_xor(ps, 1);
                ps += __shfl_xor(ps, 2);
                ps += __shfl_xor(ps, 4);
                ps += __shfl_xor(ps, 8);
                l_r[i][r] = l_r[i][r] * al + ps;
                m_r[i][r] = mn;
                alpha_[i][r] = al;
            }
        }
        // rescale O
        #pragma unroll
        for (int i = 0; i < 2; i++)
            #pragma unroll
            for (int od = 0; od < 4; od++)
                #pragma unroll
                for (int r = 0; r < 4; r++)
                    Oacc[i][od][r] *= alpha_[i][r];

        // ---- P (C layout) -> LDS -> A layout ----
        bf16_t* Pw = Ps[wid];
        #pragma unroll
        for (int i = 0; i < 2; i++)
            #pragma unroll
            for (int kj = 0; kj < 4; kj++)
                #pragma unroll
                for (int r = 0; r < 4; r++)
                    Pw[(i * 16 + lq * 4 + r) * KR + kj * 16 + col] = (bf16_t)Sacc[i][kj][r];
        __syncthreads();

        // ---- O += P V ----
        #pragma unroll
        for (int m = 0; m < 2; m++) {
            bf16x8 afp[2];
            #pragma unroll
            for (int i = 0; i < 2; i++)
                afp[i] = *(const bf16x8*)(Pw + (i * 16 + col) * KR + m * 32 + lq * 8);
            #pragma unroll
            for (int od = 0; od < 4; od++) {
                bf16x8 vf = *(const bf16x8*)(Vt + (od * 16 + col) * KR + m * 32 + lq * 8);
                #pragma unroll
                for (int i = 0; i < 2; i++)
                    Oacc[i][od] = __builtin_amdgcn_mfma_f32_16x16x32_bf16(afp[i], vf, Oacc[i][od], 0, 0, 0);
            }
        }
        __syncthreads();   // protect Ks/Vt/Ps before next chunk staging
    }

    // ---- epilogue: O/l -> LDS (row-major) -> coalesced global ----
    bf16_t* Pw = Ps[wid];
    float inv[2][4];
    #pragma unroll
    for (int i = 0; i < 2; i++)
        #pragma unroll
        for (int r = 0; r < 4; r++) inv[i][r] = 1.f / l_r[i][r];
    #pragma unroll
    for (int i = 0; i < 2; i++)
        #pragma unroll
        for (int od = 0; od < 4; od++)
            #pragma unroll
            for (int r = 0; r < 4; r++)
                Pw[(i * 16 + lq * 4 + r) * KR + od * 16 + col] = (bf16_t)(Oacc[i][od][r] * inv[i][r]);
    __syncthreads();
    #pragma unroll
    for (int it = 0; it < 4; it++) {
        int idx = lane + it * 64;
        int row = idx >> 3, g = idx & 7;
        int gs = bi * BLK + qr0 + row;
        *(bf16x8*)(o + ((size_t)(b * SEQ + gs)) * WIDTH + h * DH + g * 8) =
            *(const bf16x8*)(Pw + row * KR + g * 8);
    }
}

// delim/dynamics rows attend only to themselves: o = v
__global__ __launch_bounds__(256) void attn_copy(
    const bf16_t* __restrict__ qkv, bf16_t* __restrict__ o) {
    int idx = blockIdx.x * 256 + threadIdx.x;   // 864 rows * 64 segs
    if (idx >= BATCH * NFR * 18 * 64) return;
    int seg = idx & 63;
    int row = idx >> 6;
    int b = row / (NFR * 18);
    int rem = row % (NFR * 18);
    int bi = rem / 18;
    int r = rem % 18 + NF;
    int s = bi * BLK + r;
    const bf16_t* src = qkv + ((size_t)(b * SEQ + s) * (3 * WIDTH) + 2 * WIDTH + seg * 8);
    bf16_t* dst = o + ((size_t)(b * SEQ + s) * WIDTH + seg * 8);
    *(bf16x8*)dst = *(const bf16x8*)src;
}

// ---------------- gather frame-token rows (fp32 h -> bf16) ----------------
__global__ __launch_bounds__(256) void gather_kernel(
    const float* __restrict__ h, bf16_t* __restrict__ out) {
    int idx = blockIdx.x * 256 + threadIdx.x;   // OUTROWS*WIDTH/4
    if (idx >= OUTROWS * WIDTH / 4) return;
    int w = (idx * 4) & (WIDTH - 1);
    int t = (idx * 4) >> 9;
    int i = t % NF; t /= NF;
    int n = t % NFR;
    int b = t / NFR;
    int s = n * BLK + i;
    float4 v = *(const float4*)(h + ((size_t)(b * SEQ + s)) * WIDTH + w);
    bf16x4 o = { (bf16_t)v.x, (bf16_t)v.y, (bf16_t)v.z, (bf16_t)v.w };
    *(bf16x4*)(out + (size_t)idx * 4) = o;
}

extern "C" void kernel_launch(void* const* d_in, const int* in_sizes, int n_in,
                              void* d_out, int out_size, void* d_ws, size_t ws_size,
                              hipStream_t stream) {
    const float* x     = (const float*)d_in[0];
    const float* f     = (const float*)d_in[1];
    const float* delim = (const float*)d_in[2];
    const float* ln1_s = (const float*)d_in[3];
    const float* ln1_b = (const float*)d_in[4];
    const float* w_qkv = (const float*)d_in[5];
    const float* b_qkv = (const float*)d_in[6];
    const float* w_out = (const float*)d_in[7];
    const float* b_out = (const float*)d_in[8];
    const float* ln2_s = (const float*)d_in[9];
    const float* ln2_b = (const float*)d_in[10];
    const float* w_fc  = (const float*)d_in[11];
    const float* b_fc  = (const float*)d_in[12];
    const float* w_pr  = (const float*)d_in[13];
    const float* b_pr  = (const float*)d_in[14];
    const float* w_hd  = (const float*)d_in[15];
    float* out = (float*)d_out;

    // workspace layout (bytes): total ~68.1 MB (known-good ws >= 86.1 MB)
    char* base = (char*)d_ws;
    float*  h      = (float*)base;                 base += (size_t)MROWS * WIDTH * 4;     // 14.35 MB
    bf16_t* a_bf   = (bf16_t*)base;                base += (size_t)MROWS * WIDTH * 2;     // 7.18 MB
    bf16_t* big_bf = (bf16_t*)base;                base += (size_t)MROWS * 2048 * 2;      // 28.7 MB (qkv 1536 / gelu 2048 shared)
    bf16_t* wi_bf  = (bf16_t*)base;                base += (size_t)LAYERS * 1536 * 512 * 2;
    bf16_t* wo_bf  = (bf16_t*)base;                base += (size_t)LAYERS * 512 * 512 * 2;
    bf16_t* wh_bf  = (bf16_t*)base;                base += (size_t)VOCAB * 512 * 2;
    bf16_t* wfc_bf = (bf16_t*)base;                base += (size_t)2048 * 512 * 2;
    bf16_t* wpr_bf = (bf16_t*)base;                base += (size_t)512 * 2048 * 2;

    cast_kernel<<<LAYERS * 1536 * 512 / 1024, 256, 0, stream>>>(w_qkv, wi_bf, LAYERS * 1536 * 512 / 4);
    cast_kernel<<<LAYERS * 512 * 512 / 1024, 256, 0, stream>>>(w_out, wo_bf, LAYERS * 512 * 512 / 4);
    cast_kernel<<<VOCAB * 512 / 1024, 256, 0, stream>>>(w_hd, wh_bf, VOCAB * 512 / 4);

    embed_kernel<<<(BATCH * SEQ * WIDTH) / 256, 256, 0, stream>>>(x, f, delim, h);

    const int MT = (MROWS + TM - 1) / TM;   // 55
    for (int l = 0; l < LAYERS; l++) {
        ln_kernel<<<MROWS, 256, 0, stream>>>(h, ln1_s + l * WIDTH, ln1_b + l * WIDTH, a_bf);
        gemm_bf16<3><<<dim3(1536 / TN, MT), 256, 0, stream>>>(
            a_bf, wi_bf + (size_t)l * 1536 * 512, b_qkv + (size_t)l * 1536,
            nullptr, big_bf, MROWS, 1536, 512);
        attn_mfma<<<dim3(NFR, HEADS, BATCH), 256, 0, stream>>>(big_bf, a_bf);
        attn_copy<<<(BATCH * NFR * 18 * 64 + 255) / 256, 256, 0, stream>>>(big_bf, a_bf);
        gemm_bf16<2><<<dim3(512 / TN, MT), 256, 0, stream>>>(
            a_bf, wo_bf + (size_t)l * 512 * 512, b_out + (size_t)l * 512,
            h, nullptr, MROWS, 512, 512);
        ln_kernel<<<MROWS, 256, 0, stream>>>(h, ln2_s + l * WIDTH, ln2_b + l * WIDTH, a_bf);
        cast_kernel<<<2048 * 512 / 1024, 256, 0, stream>>>(w_fc + (size_t)l * 2048 * 512, wfc_bf, 2048 * 512 / 4);
        gemm_bf16<1><<<dim3(2048 / TN, MT), 256, 0, stream>>>(
            a_bf, wfc_bf, b_fc + (size_t)l * 2048,
            nullptr, big_bf, MROWS, 2048, 512);
        cast_kernel<<<512 * 2048 / 1024, 256, 0, stream>>>(w_pr + (size_t)l * 512 * 2048, wpr_bf, 512 * 2048 / 4);
        gemm_bf16<2><<<dim3(512 / TN, MT), 256, 0, stream>>>(
            big_bf, wpr_bf, b_pr + (size_t)l * 512,
            h, nullptr, MROWS, 512, 2048);
    }

    gather_kernel<<<(OUTROWS * WIDTH / 4) / 256, 256, 0, stream>>>(h, a_bf);
    gemm_bf16<0><<<dim3(VOCAB / TN, OUTROWS / TM), 256, 0, stream>>>(
        a_bf, wh_bf, nullptr, out, nullptr, OUTROWS, VOCAB, 512);
}